// Round 4
// baseline (371.837 us; speedup 1.0000x reference)
//
#include <hip/hip_runtime.h>

typedef unsigned long long u64;

// ws layout (float offsets):
#define OFF_A    0      // 510: -0.5*||c||^2 per combo, level-major (off_L = 2^L-2)
#define OFF_DT   512    // dT[c*8+s]  = w[r1[s]][c]-w[r0[s]][c]
#define OFF_V0T  1536   // v0T[c*8+s] = w[r0[s]][c]
#define OFF_BTT  2560   // btt[c*8+l] = sum_{s<=l} w[r0[s]][c]   (transposed base prefix)
#define OFF_PART 3584   // partial[8][512] block loss sums
#define OFF_CNT  7680   // int completion counter (zeroed by build_tables)

__device__ __forceinline__ float warp_sum(float v) {
  #pragma unroll
  for (int off = 32; off > 0; off >>= 1) v += __shfl_down(v, off);
  return v;
}

// ---------------- Kernel A: build tables + zero ticket counter ----------------------------
__global__ __launch_bounds__(64) void build_tables(const float* __restrict__ w,
                                                   float* __restrict__ wsf) {
  const int r0[8] = {0, 3, 4, 5, 6, 7, 8, 9};
  int e = blockIdx.x;
  int t = threadIdx.x;
  if (e < 510) {
    int ep2 = e + 2;
    int L = 31 - __clz(ep2);        // level 1..8
    int i = ep2 - (1 << L);         // combo index, b1 = MSB
    float acc = 0.f;
    #pragma unroll
    for (int half = 0; half < 2; ++half) {
      int cc = t + half * 64;
      float v = 0.f;
      for (int s = 0; s < L; ++s) {
        int b = (i >> (L - 1 - s)) & 1;
        v += w[(r0[s] + b) * 128 + cc];
      }
      acc += v * v;
    }
    acc = warp_sum(acc);
    if (t == 0) wsf[OFF_A + e] = -0.5f * acc;
  } else {
    #pragma unroll
    for (int half = 0; half < 2; ++half) {
      int cc = t + half * 64;
      float basesum = 0.f;
      #pragma unroll
      for (int s = 0; s < 8; ++s) {
        float w0 = w[r0[s] * 128 + cc];
        float w1 = w[(r0[s] + 1) * 128 + cc];
        wsf[OFF_V0T + cc * 8 + s] = w0;
        wsf[OFF_DT + cc * 8 + s] = w1 - w0;
        basesum += w0;
        wsf[OFF_BTT + cc * 8 + s] = basesum;
      }
    }
    if (t == 0) ((int*)wsf)[OFF_CNT] = 0;
  }
}

// ---------------- Guaranteed-unroll level search (all indices compile-time) ---------------
template <int L, int I, int N>
struct SU {
  static __device__ __forceinline__ void run(const float* Al, const float* T,
                                             const float* S, float& bs, int& bi) {
    float dot;
    if constexpr (L <= 4) {
      dot = T[I << (4 - L)];
    } else {
      dot = T[I >> (L - 4)] + S[(I & ((1 << (L - 4)) - 1)) << (8 - L)];
    }
    float sc = dot + Al[I];
    if (sc > bs) { bs = sc; bi = I; }   // strict > keeps lowest index on ties
    SU<L, I + 1, N>::run(Al, T, S, bs, bi);
  }
};
template <int L, int N>
struct SU<L, N, N> {
  static __device__ __forceinline__ void run(const float*, const float*, const float*,
                                             float&, int&) {}
};

template <int L>
__device__ __forceinline__ void search_level(const float* Al_base, const float* T,
                                             const float* S, float& bestsc, int& bestidx) {
  const float* Al = Al_base + ((1 << L) - 2);
  float bs = -3.4e38f;
  int bi = 0;
  SU<L, 0, (1 << L)>::run(Al, T, S, bs, bi);
  bestsc = bs;
  bestidx = bi;
}

// ---------------- Kernel B (fused): dots + argmax + direct 268MB write + loss -------------
__global__ __launch_bounds__(128) void fused_kernel(const float* __restrict__ in,
                                                    const float* __restrict__ tbl,
                                                    float* __restrict__ partial,
                                                    int* __restrict__ counter,
                                                    float* __restrict__ out) {
  __shared__ __align__(16) float dTl[1024];
  __shared__ __align__(16) float v0l[1024];
  __shared__ __align__(16) float btl[1024];
  __shared__ float Al[510];
  __shared__ float red[2][8];
  __shared__ int lastflag;

  int tid = threadIdx.x;
  for (int i = tid; i < 1024; i += 128) {
    dTl[i] = tbl[OFF_DT + i];
    v0l[i] = tbl[OFF_V0T + i];
    btl[i] = tbl[OFF_BTT + i];
  }
  for (int i = tid; i < 510; i += 128) Al[i] = tbl[OFF_A + i];
  __syncthreads();

  int gpos = blockIdx.x * 128 + tid;
  int b = gpos >> 12;
  int hw = gpos & 4095;
  const float* xp = in + ((size_t)b << 19) + hw;   // (B,128,64,64): channel stride 4096
  const float4* dT4 = (const float4*)dTl;
  const float4* v04 = (const float4*)v0l;

  // ---- dot products (coalesced x loads; broadcast LDS table reads) ----
  float qq[8], uu[8];
  #pragma unroll
  for (int k = 0; k < 8; ++k) { qq[k] = 0.f; uu[k] = 0.f; }
  float xx = 0.f;
  #pragma unroll 4
  for (int c = 0; c < 128; ++c) {
    float x = xp[(size_t)c << 12];
    float4 d0 = dT4[2 * c], d1 = dT4[2 * c + 1];
    float4 u0 = v04[2 * c], u1 = v04[2 * c + 1];
    xx = fmaf(x, x, xx);
    qq[0] = fmaf(x, d0.x, qq[0]); qq[1] = fmaf(x, d0.y, qq[1]);
    qq[2] = fmaf(x, d0.z, qq[2]); qq[3] = fmaf(x, d0.w, qq[3]);
    qq[4] = fmaf(x, d1.x, qq[4]); qq[5] = fmaf(x, d1.y, qq[5]);
    qq[6] = fmaf(x, d1.z, qq[6]); qq[7] = fmaf(x, d1.w, qq[7]);
    uu[0] = fmaf(x, u0.x, uu[0]); uu[1] = fmaf(x, u0.y, uu[1]);
    uu[2] = fmaf(x, u0.z, uu[2]); uu[3] = fmaf(x, u0.w, uu[3]);
    uu[4] = fmaf(x, u1.x, uu[4]); uu[5] = fmaf(x, u1.y, uu[5]);
    uu[6] = fmaf(x, u1.z, uu[6]); uu[7] = fmaf(x, u1.w, uu[7]);
  }

  // ---- subset-sum tables: T stages 1..4 (bit3<->stage1), S stages 5..8 ----
  float T[16], S[16];
  #pragma unroll
  for (int h = 0; h < 16; ++h) {
    float tv = 0.f, sv = 0.f;
    if (h & 8) { tv += qq[0]; sv += qq[4]; }
    if (h & 4) { tv += qq[1]; sv += qq[5]; }
    if (h & 2) { tv += qq[2]; sv += qq[6]; }
    if (h & 1) { tv += qq[3]; sv += qq[7]; }
    T[h] = tv; S[h] = sv;
  }

  float bsc[8];
  int bix[8];
  search_level<1>(Al, T, S, bsc[0], bix[0]);
  search_level<2>(Al, T, S, bsc[1], bix[1]);
  search_level<3>(Al, T, S, bsc[2], bix[2]);
  search_level<4>(Al, T, S, bsc[3], bix[3]);
  search_level<5>(Al, T, S, bsc[4], bix[4]);
  search_level<6>(Al, T, S, bsc[5], bix[5]);
  search_level<7>(Al, T, S, bsc[6], bix[6]);
  search_level<8>(Al, T, S, bsc[7], bix[7]);

  // ---- loss partials (deterministic, non-atomic) ----
  int wv = tid >> 6;
  float P0 = 0.f;
  #pragma unroll
  for (int l = 0; l < 8; ++l) {
    P0 += uu[l];                                   // x . base_L
    float sse = xx - 2.f * (P0 + bsc[l]);          // ||x - q||^2
    sse = warp_sum(sse);
    if ((tid & 63) == 0) red[wv][l] = sse;
  }
  __syncthreads();
  if (tid < 8) partial[tid * 512 + blockIdx.x] = red[0][tid] + red[1][tid];

  // ---- decode bits to floats (lower triangle, 36 regs) ----
  const int TRI[8] = {0, 1, 3, 6, 10, 15, 21, 28};
  float bf[36];
  #pragma unroll
  for (int l = 0; l < 8; ++l) {
    #pragma unroll
    for (int s = 0; s < 8; ++s) {
      if (s <= l) bf[TRI[l] + s] = (float)((bix[l] >> (l - s)) & 1);
    }
  }

  // ---- write phase: reconstruct q for all 8 levels, stream 268 MB ----
  const float4* bt4 = (const float4*)btl;
  size_t obase = ((size_t)b << 19) + hw;
  #pragma unroll 2
  for (int c = 0; c < 128; ++c) {
    float4 d0 = dT4[2 * c], d1 = dT4[2 * c + 1];
    float4 t0 = bt4[2 * c], t1 = bt4[2 * c + 1];
    float dv[8] = {d0.x, d0.y, d0.z, d0.w, d1.x, d1.y, d1.z, d1.w};
    float bt[8] = {t0.x, t0.y, t0.z, t0.w, t1.x, t1.y, t1.z, t1.w};
    size_t cbase = obase + ((size_t)c << 12);
    #pragma unroll
    for (int l = 0; l < 8; ++l) {
      float v = bt[l];
      #pragma unroll
      for (int s = 0; s < 8; ++s) {
        if (s <= l) v = fmaf(bf[TRI[l] + s], dv[s], v);
      }
      out[cbase + ((size_t)l << 23)] = v;          // coalesced 256B per wave-inst
    }
  }

  // ---- last-block loss finalize (ticket pattern) ----
  __threadfence();
  __syncthreads();
  if (tid == 0) lastflag = (atomicAdd(counter, 1) == 511);
  __syncthreads();
  if (lastflag) {
    __threadfence();
    if (tid < 64) {
      const float CO[8] = {1.5f, 1.2f, 1.0f, 0.9f, 0.82f, 0.69f, 0.65f, 0.56f};
      int l = tid >> 3;
      int j = tid & 7;
      float s = 0.f;
      #pragma unroll 4
      for (int k = 0; k < 64; ++k) s += partial[l * 512 + j + k * 8];
      s += __shfl_down(s, 4);
      s += __shfl_down(s, 2);
      s += __shfl_down(s, 1);
      if (j == 0)
        out[67108864ull + l] = (CO[l] + 0.4f) * s * (1.0f / 8388608.0f);
    }
  }
}

extern "C" void kernel_launch(void* const* d_in, const int* in_sizes, int n_in,
                              void* d_out, int out_size, void* d_ws, size_t ws_size,
                              hipStream_t stream) {
  const float* in = (const float*)d_in[0];   // (16,128,64,64) fp32
  const float* w  = (const float*)d_in[1];   // (256,128) fp32
  float* wsf = (float*)d_ws;
  float* partial = wsf + OFF_PART;
  int* counter = ((int*)wsf) + OFF_CNT;
  float* out = (float*)d_out;

  build_tables<<<511, 64, 0, stream>>>(w, wsf);
  fused_kernel<<<512, 128, 0, stream>>>(in, wsf, partial, counter, out);
}